// Round 12
// baseline (138.062 us; speedup 1.0000x reference)
//
#include <hip/hip_runtime.h>
#include <hip/hip_bf16.h>

#define D_  2048
#define IN_ 512
#define T_  4096
#define G4_ 8192

typedef __attribute__((ext_vector_type(4))) float f32x4;
typedef __attribute__((ext_vector_type(8))) short s16x8;
typedef unsigned short u16;

// ws layout (float offsets)
#define WS_PROD    0                        // T_
#define WS_Q       (T_)                     // D_
#define WS_X       (T_ + D_)                // D_+IN_ : [context | data]
#define WS_PARTIAL (WS_X + D_ + IN_)        // T_*16
#define WS_SCORE   (WS_PARTIAL + T_*16)     // T_ (unused, layout stability)
#define WS_GATES   (WS_SCORE + T_)          // G4_ (unused, layout stability)
#define WS_G2      (WS_GATES + G4_)         // G4_  (Whh@h0 partial)
#define WS_FC      (WS_G2 + G4_)            // D_
#define WS_L1      (WS_FC + D_)             // D_
#define WS_HN      (WS_L1 + D_)             // D_
#define WS_BF16    (WS_HN + D_)             // bf16 region (encB, UwB)
#define WS_FAST_BYTES ((size_t)WS_BF16 * 4 + ((size_t)T_ * D_ + (size_t)D_ * D_) * 2)

typedef const __attribute__((address_space(1))) void gas_t;
typedef __attribute__((address_space(3))) void las_t;

__device__ inline u16 bfbits(float f) {
  union { __hip_bfloat16 b; u16 s; } u; u.b = __float2bfloat16(f); return u.s;
}
__device__ inline float bf2f(u16 s) {
  union { unsigned u; float f; } v; v.u = ((unsigned)s) << 16; return v.f;
}

// full-row dot by one wave; returns sum in all lanes
__device__ inline float wave_dot4(const float* __restrict__ w,
                                  const float* __restrict__ x, int n4, int lane) {
  float s = 0.f;
  const f32x4* w4 = (const f32x4*)w;
  const f32x4* x4 = (const f32x4*)x;
  for (int c = lane; c < n4; c += 64) {
    f32x4 a = w4[c], b = x4[c];
    s += a[0]*b[0] + a[1]*b[1] + a[2]*b[2] + a[3]*b[3];
  }
  #pragma unroll
  for (int m = 32; m >= 1; m >>= 1) s += __shfl_xor(s, m, 64);
  return s;
}

// ---- kernel 1: bf16 convert (grid-stride, max BW) + prod + zeroX + data + q ----
__global__ __launch_bounds__(256) void k_convert(const float* __restrict__ Ww,
    const float* __restrict__ h0, const float* __restrict__ pi,
    const float* __restrict__ data, const int* __restrict__ ip,
    const float* __restrict__ enc, const float* __restrict__ Uw,
    int do_convert, float* __restrict__ ws) {
  const int gidx = blockIdx.x * 256 + threadIdx.x;   // 0..262143
  const int nth = 1024 * 256;
  if (do_convert) {
    u16* encB = (u16*)(ws + WS_BF16);
    u16* UwB  = encB + (size_t)T_ * D_;
    for (int c = gidx; c < (T_ * D_) / 8; c += nth) {
      const size_t base = (size_t)c * 8;
      f32x4 v0 = *(const f32x4*)(enc + base);
      f32x4 v1 = *(const f32x4*)(enc + base + 4);
      u16 t[8];
      #pragma unroll
      for (int e = 0; e < 4; ++e) { t[e] = bfbits(v0[e]); t[4 + e] = bfbits(v1[e]); }
      *(s16x8*)&encB[base] = *(s16x8*)&t[0];
    }
    for (int c = gidx; c < (D_ * D_) / 8; c += nth) {
      const size_t base = (size_t)c * 8;
      f32x4 v0 = *(const f32x4*)(Uw + base);
      f32x4 v1 = *(const f32x4*)(Uw + base + 4);
      u16 t[8];
      #pragma unroll
      for (int e = 0; e < 4; ++e) { t[e] = bfbits(v0[e]); t[4 + e] = bfbits(v1[e]); }
      *(s16x8*)&UwB[base] = *(s16x8*)&t[0];
    }
  }
  const int op = ip[0] + 1;
  if (gidx < T_) {
    float p = 0.f;
    if (gidx >= op - 1) {
      int idx = op + T_ - gidx - 2;
      idx = idx < 0 ? 0 : (idx > T_ - 1 ? T_ - 1 : idx);
      p = pi[idx];
    }
    ws[WS_PROD + gidx] = p;
  }
  if (gidx < D_) ws[WS_X + gidx] = 0.f;          // context atomic target
  if (gidx < IN_) ws[WS_X + D_ + gidx] = data[gidx];
  const int gw = gidx >> 6, lane = gidx & 63;
  if (gw < D_) {
    float s = wave_dot4(Ww + (size_t)gw * D_, h0, D_ / 4, lane);
    if (lane == 0) ws[WS_Q + gw] = s;
  }
}

// ---- kernel 2 (fast): bf16 GEMM via global_load_lds, swizzled LDS (r8 exact) ----
__global__ __launch_bounds__(512, 4) void k_gemm_bf16(
    const float* __restrict__ Vw, const float* __restrict__ h0,
    const float* __restrict__ Whh, float* __restrict__ ws) {
  __shared__ __align__(16) u16 Ah[128 * 64];
  __shared__ __align__(16) u16 Bh[128 * 64];
  const u16* encB = (const u16*)(ws + WS_BF16);
  const u16* UwB  = encB + (size_t)T_ * D_;
  const int tid = threadIdx.x, lane = tid & 63, wid = tid >> 6;
  const int wr = wid >> 2, wc = wid & 3;         // 2 x 4 wave grid
  const int g = lane >> 4, lr = lane & 15;
  const int bid = blockIdx.x;
  // XCD-chunked swizzle: XCD k owns mb in {4k..4k+3} for all nb
  const int wgid = (bid & 7) * 64 + (bid >> 3);
  const int mb = wgid >> 4, nb = wgid & 15;

  f32x4 acc[4][2];
  #pragma unroll
  for (int m = 0; m < 4; ++m)
    #pragma unroll
    for (int n = 0; n < 2; ++n) acc[m][n] = (f32x4){0.f, 0.f, 0.f, 0.f};

  // staging: 1024 16B-chunks per 128x64 tile; thread covers c = tid, tid+512.
  // rule #21: linear LDS dest + inverse-swizzled global source + swizzled read.
  const int c0 = tid,        r0 = c0 >> 3, s0 = (c0 & 7) ^ (r0 & 7);
  const int c1 = tid + 512,  r1 = c1 >> 3, s1 = (c1 & 7) ^ (r1 & 7);
  const u16* ga0 = encB + (size_t)(mb * 128 + r0) * D_ + s0 * 8;
  const u16* ga1 = encB + (size_t)(mb * 128 + r1) * D_ + s1 * 8;
  const u16* gb0 = UwB  + (size_t)(nb * 128 + r0) * D_ + s0 * 8;
  const u16* gb1 = UwB  + (size_t)(nb * 128 + r1) * D_ + s1 * 8;
  u16* la0 = &Ah[c0 * 8]; u16* la1 = &Ah[c1 * 8];
  u16* lb0 = &Bh[c0 * 8]; u16* lb1 = &Bh[c1 * 8];

  for (int ks = 0; ks < D_ / 64; ++ks) {
    __syncthreads();   // previous iteration's LDS reads complete
    __builtin_amdgcn_global_load_lds((gas_t*)(ga0 + ks * 64), (las_t*)la0, 16, 0, 0);
    __builtin_amdgcn_global_load_lds((gas_t*)(ga1 + ks * 64), (las_t*)la1, 16, 0, 0);
    __builtin_amdgcn_global_load_lds((gas_t*)(gb0 + ks * 64), (las_t*)lb0, 16, 0, 0);
    __builtin_amdgcn_global_load_lds((gas_t*)(gb1 + ks * 64), (las_t*)lb1, 16, 0, 0);
    __syncthreads();   // compiler drains vmcnt before barrier
    #pragma unroll
    for (int kk = 0; kk < 2; ++kk) {
      const int koff = kk * 64 + g * 16;   // byte offset within 128B row
      s16x8 af[4], bf[2];
      #pragma unroll
      for (int m = 0; m < 4; ++m) {
        const int r = wr * 64 + m * 16 + lr;
        af[m] = *(const s16x8*)((const char*)Ah + r * 128 + (koff ^ ((r & 7) << 4)));
      }
      #pragma unroll
      for (int n = 0; n < 2; ++n) {
        const int r = wc * 32 + n * 16 + lr;
        bf[n] = *(const s16x8*)((const char*)Bh + r * 128 + (koff ^ ((r & 7) << 4)));
      }
      #pragma unroll
      for (int m = 0; m < 4; ++m)
        #pragma unroll
        for (int n = 0; n < 2; ++n)
          acc[m][n] = __builtin_amdgcn_mfma_f32_16x16x32_bf16(af[m], bf[n], acc[m][n], 0, 0, 0);
    }
  }

  // epilogue: per-row partial of score = sum_d V[d]*tanh(q[d] + prod[t]*C[t][d])
  const float* q    = ws + WS_Q;
  const float* prod = ws + WS_PROD;
  float Vv[2], qv[2];
  #pragma unroll
  for (int n = 0; n < 2; ++n) {
    const int d = nb * 128 + wc * 32 + n * 16 + lr;
    Vv[n] = Vw[d]; qv[n] = q[d];
  }
  __syncthreads();
  float* red = (float*)Ah;   // 128 x 4 floats
  #pragma unroll
  for (int m = 0; m < 4; ++m) {
    #pragma unroll
    for (int r = 0; r < 4; ++r) {
      const int t_loc = wr * 64 + m * 16 + g * 4 + r;
      const float p = prod[mb * 128 + t_loc];
      float s = Vv[0] * tanhf(qv[0] + p * acc[m][0][r])
              + Vv[1] * tanhf(qv[1] + p * acc[m][1][r]);
      s += __shfl_xor(s, 1, 64);
      s += __shfl_xor(s, 2, 64);
      s += __shfl_xor(s, 4, 64);
      s += __shfl_xor(s, 8, 64);
      if (lr == 0) red[t_loc * 4 + wc] = s;
    }
  }
  __syncthreads();
  if (tid < 128) {
    const float s = red[tid * 4] + red[tid * 4 + 1] + red[tid * 4 + 2] + red[tid * 4 + 3];
    ws[WS_PARTIAL + (size_t)(mb * 128 + tid) * 16 + nb] = s;
  }

  // Whh @ h0 tail: 16 rows per block (overlaps other blocks' GEMM)
  const int rbase = bid * 16 + wid * 2;
  #pragma unroll
  for (int rr = 0; rr < 2; ++rr) {
    const int row = rbase + rr;
    float s = wave_dot4(Whh + (size_t)row * D_, h0, D_ / 4, lane);
    if (lane == 0) ws[WS_G2 + row] = s;
  }
}

// ---- kernel 2 (fallback): fp32-load in-kernel-convert GEMM ----
__global__ __launch_bounds__(512, 4) void k_gemm_f32(
    const float* __restrict__ enc, const float* __restrict__ Uw,
    const float* __restrict__ Vw, const float* __restrict__ h0,
    const float* __restrict__ Whh, float* __restrict__ ws) {
  __shared__ __align__(16) u16 sbuf[2 * 128 * 40];
  u16* Ah = sbuf;
  u16* Bh = sbuf + 128 * 40;
  const int tid = threadIdx.x;
  const int lane = tid & 63, wid = tid >> 6;
  const int wr = wid >> 2, wc = wid & 3;
  const int g = lane >> 4, lr = lane & 15;
  const int mb = blockIdx.x, nb = blockIdx.y;

  f32x4 acc[4][2];
  #pragma unroll
  for (int m = 0; m < 4; ++m)
    #pragma unroll
    for (int n = 0; n < 2; ++n) acc[m][n] = (f32x4){0.f, 0.f, 0.f, 0.f};

  const int srow = tid >> 2;
  const int scol = (tid & 3) * 8;
  const float* pa0 = enc + (size_t)(mb * 128 + srow) * D_ + scol;
  const float* pb0 = Uw  + (size_t)(nb * 128 + srow) * D_ + scol;
  const int sidx = srow * 40 + scol;

  f32x4 an0 = *(const f32x4*)(pa0);
  f32x4 an1 = *(const f32x4*)(pa0 + 4);
  f32x4 bn0 = *(const f32x4*)(pb0);
  f32x4 bn1 = *(const f32x4*)(pb0 + 4);

  for (int ks = 0; ks < 64; ++ks) {
    f32x4 a0 = an0, a1 = an1, b0 = bn0, b1 = bn1;
    if (ks < 63) {
      an0 = *(const f32x4*)(pa0 + (ks + 1) * 32);
      an1 = *(const f32x4*)(pa0 + (ks + 1) * 32 + 4);
      bn0 = *(const f32x4*)(pb0 + (ks + 1) * 32);
      bn1 = *(const f32x4*)(pb0 + (ks + 1) * 32 + 4);
    }
    __syncthreads();
    __align__(16) u16 ah[8], bh[8];
    #pragma unroll
    for (int e = 0; e < 4; ++e) {
      ah[e] = bfbits(a0[e]); ah[4 + e] = bfbits(a1[e]);
      bh[e] = bfbits(b0[e]); bh[4 + e] = bfbits(b1[e]);
    }
    *(s16x8*)&Ah[sidx] = *(s16x8*)&ah[0];
    *(s16x8*)&Bh[sidx] = *(s16x8*)&bh[0];
    __syncthreads();

    s16x8 af[4], bf[2];
    #pragma unroll
    for (int m = 0; m < 4; ++m)
      af[m] = *(const s16x8*)&Ah[(wr * 64 + m * 16 + lr) * 40 + g * 8];
    #pragma unroll
    for (int n = 0; n < 2; ++n)
      bf[n] = *(const s16x8*)&Bh[(wc * 32 + n * 16 + lr) * 40 + g * 8];
    #pragma unroll
    for (int m = 0; m < 4; ++m)
      #pragma unroll
      for (int n = 0; n < 2; ++n)
        acc[m][n] = __builtin_amdgcn_mfma_f32_16x16x32_bf16(af[m], bf[n], acc[m][n], 0, 0, 0);
  }

  const float* q    = ws + WS_Q;
  const float* prod = ws + WS_PROD;
  float Vv[2], qv[2];
  #pragma unroll
  for (int n = 0; n < 2; ++n) {
    const int d = nb * 128 + wc * 32 + n * 16 + lr;
    Vv[n] = Vw[d]; qv[n] = q[d];
  }
  __syncthreads();
  float* red = (float*)sbuf;
  #pragma unroll
  for (int m = 0; m < 4; ++m) {
    #pragma unroll
    for (int r = 0; r < 4; ++r) {
      const int t_loc = wr * 64 + m * 16 + g * 4 + r;
      const float p = prod[mb * 128 + t_loc];
      float s = Vv[0] * tanhf(qv[0] + p * acc[m][0][r])
              + Vv[1] * tanhf(qv[1] + p * acc[m][1][r]);
      s += __shfl_xor(s, 1, 64);
      s += __shfl_xor(s, 2, 64);
      s += __shfl_xor(s, 4, 64);
      s += __shfl_xor(s, 8, 64);
      if (lr == 0) red[t_loc * 4 + wc] = s;
    }
  }
  __syncthreads();
  if (tid < 128) {
    const float s = red[tid * 4] + red[tid * 4 + 1] + red[tid * 4 + 2] + red[tid * 4 + 3];
    ws[WS_PARTIAL + (size_t)(mb * 128 + tid) * 16 + nb] = s;
  }
  const int flat = blockIdx.y * gridDim.x + blockIdx.x;
  const int rbase = flat * 16 + wid * 2;
  #pragma unroll
  for (int rr = 0; rr < 2; ++rr) {
    const int row = rbase + rr;
    float s = wave_dot4(Whh + (size_t)row * D_, h0, D_ / 4, lane);
    if (lane == 0) ws[WS_G2 + row] = s;
  }
}

// ---- kernel 3: per-block partial-reduce + mask + local softmax + context chunk ----
//      block (bx,by): d = bx*256+tid, t-chunk = [by*256, by*256+256)
__global__ __launch_bounds__(256) void k_ctxattn_bf16(const int* __restrict__ ip,
                                                      float* __restrict__ ws) {
  __shared__ float sred[4];
  __shared__ float satt[256];
  const u16* encB = (const u16*)(ws + WS_BF16);
  const int tid = threadIdx.x, lane = tid & 63, wid = tid >> 6;
  const int op = ip[0] + 1;
  // reduce partials -> masked score for t = tid + j*256 (all T, per block)
  float lv[16];
  #pragma unroll
  for (int j = 0; j < 16; ++j) {
    const int t = tid + j * 256;
    const f32x4* p = (const f32x4*)(ws + WS_PARTIAL + (size_t)t * 16);
    f32x4 p0 = p[0], p1 = p[1], p2 = p[2], p3 = p[3];
    float s = (p0[0]+p0[1]+p0[2]+p0[3]) + (p1[0]+p1[1]+p1[2]+p1[3])
            + (p2[0]+p2[1]+p2[2]+p2[3]) + (p3[0]+p3[1]+p3[2]+p3[3]);
    lv[j] = (t < op) ? 0.f : s;
  }
  float mx = lv[0];
  #pragma unroll
  for (int j = 1; j < 16; ++j) mx = fmaxf(mx, lv[j]);
  #pragma unroll
  for (int m = 32; m >= 1; m >>= 1) mx = fmaxf(mx, __shfl_xor(mx, m, 64));
  if (lane == 0) sred[wid] = mx;
  __syncthreads();
  mx = fmaxf(fmaxf(sred[0], sred[1]), fmaxf(sred[2], sred[3]));
  __syncthreads();
  float ls = 0.f;
  #pragma unroll
  for (int j = 0; j < 16; ++j) ls += expf(lv[j] - mx);
  #pragma unroll
  for (int m = 32; m >= 1; m >>= 1) ls += __shfl_xor(ls, m, 64);
  if (lane == 0) sred[wid] = ls;
  __syncthreads();
  const float inv = 1.f / (sred[0] + sred[1] + sred[2] + sred[3]);
  // this thread's own-chunk score is lv[blockIdx.y]
  satt[tid] = expf(lv[blockIdx.y] - mx) * inv;
  __syncthreads();
  const int t0 = blockIdx.y * 256;
  const int d = blockIdx.x * 256 + threadIdx.x;
  float s = 0.f;
  for (int t = 0; t < 256; ++t) s += satt[t] * bf2f(encB[(size_t)(t0 + t) * D_ + d]);
  atomicAdd(&ws[WS_X + d], s);
}
__global__ __launch_bounds__(256) void k_ctxattn_f32(const int* __restrict__ ip,
                                                     const float* __restrict__ enc,
                                                     float* __restrict__ ws) {
  __shared__ float sred[4];
  __shared__ float satt[256];
  const int tid = threadIdx.x, lane = tid & 63, wid = tid >> 6;
  const int op = ip[0] + 1;
  float lv[16];
  #pragma unroll
  for (int j = 0; j < 16; ++j) {
    const int t = tid + j * 256;
    const f32x4* p = (const f32x4*)(ws + WS_PARTIAL + (size_t)t * 16);
    f32x4 p0 = p[0], p1 = p[1], p2 = p[2], p3 = p[3];
    float s = (p0[0]+p0[1]+p0[2]+p0[3]) + (p1[0]+p1[1]+p1[2]+p1[3])
            + (p2[0]+p2[1]+p2[2]+p2[3]) + (p3[0]+p3[1]+p3[2]+p3[3]);
    lv[j] = (t < op) ? 0.f : s;
  }
  float mx = lv[0];
  #pragma unroll
  for (int j = 1; j < 16; ++j) mx = fmaxf(mx, lv[j]);
  #pragma unroll
  for (int m = 32; m >= 1; m >>= 1) mx = fmaxf(mx, __shfl_xor(mx, m, 64));
  if (lane == 0) sred[wid] = mx;
  __syncthreads();
  mx = fmaxf(fmaxf(sred[0], sred[1]), fmaxf(sred[2], sred[3]));
  __syncthreads();
  float ls = 0.f;
  #pragma unroll
  for (int j = 0; j < 16; ++j) ls += expf(lv[j] - mx);
  #pragma unroll
  for (int m = 32; m >= 1; m >>= 1) ls += __shfl_xor(ls, m, 64);
  if (lane == 0) sred[wid] = ls;
  __syncthreads();
  const float inv = 1.f / (sred[0] + sred[1] + sred[2] + sred[3]);
  satt[tid] = expf(lv[blockIdx.y] - mx) * inv;
  __syncthreads();
  const int t0 = blockIdx.y * 256;
  const int d = blockIdx.x * 256 + threadIdx.x;
  float s = 0.f;
  for (int t = 0; t < 256; ++t) s += satt[t] * enc[(size_t)(t0 + t) * D_ + d];
  atomicAdd(&ws[WS_X + d], s);
}

// ---- kernel 4: fused LSTM gates + cell (r8 version: full-row dot vs [ctx|data]) ----
__global__ __launch_bounds__(256) void k_gatecell(const float* __restrict__ Wih,
    const float* __restrict__ bih, const float* __restrict__ bhh,
    const float* __restrict__ c0, float* __restrict__ ws, float* __restrict__ out) {
  const int wid = threadIdx.x >> 6, lane = threadIdx.x & 63;
  const int d = blockIdx.x * 4 + wid;            // 0..2047
  const f32x4* x4 = (const f32x4*)(ws + WS_X);
  const f32x4* r0 = (const f32x4*)(Wih + (size_t)(0 * D_ + d) * (D_ + IN_));
  const f32x4* r1 = (const f32x4*)(Wih + (size_t)(1 * D_ + d) * (D_ + IN_));
  const f32x4* r2 = (const f32x4*)(Wih + (size_t)(2 * D_ + d) * (D_ + IN_));
  const f32x4* r3 = (const f32x4*)(Wih + (size_t)(3 * D_ + d) * (D_ + IN_));
  float s0 = 0.f, s1 = 0.f, s2 = 0.f, s3 = 0.f;
  for (int c = lane; c < (D_ + IN_) / 4; c += 64) {
    f32x4 x = x4[c];
    f32x4 a0 = r0[c], a1 = r1[c], a2 = r2[c], a3 = r3[c];
    s0 += a0[0]*x[0] + a0[1]*x[1] + a0[2]*x[2] + a0[3]*x[3];
    s1 += a1[0]*x[0] + a1[1]*x[1] + a1[2]*x[2] + a1[3]*x[3];
    s2 += a2[0]*x[0] + a2[1]*x[1] + a2[2]*x[2] + a2[3]*x[3];
    s3 += a3[0]*x[0] + a3[1]*x[1] + a3[2]*x[2] + a3[3]*x[3];
  }
  #pragma unroll
  for (int m = 32; m >= 1; m >>= 1) {
    s0 += __shfl_xor(s0, m, 64);
    s1 += __shfl_xor(s1, m, 64);
    s2 += __shfl_xor(s2, m, 64);
    s3 += __shfl_xor(s3, m, 64);
  }
  if (lane == 0) {
    const float gi = s0 + ws[WS_G2 + 0 * D_ + d] + bih[0 * D_ + d] + bhh[0 * D_ + d];
    const float gf = s1 + ws[WS_G2 + 1 * D_ + d] + bih[1 * D_ + d] + bhh[1 * D_ + d];
    const float gg = s2 + ws[WS_G2 + 2 * D_ + d] + bih[2 * D_ + d] + bhh[2 * D_ + d];
    const float go = s3 + ws[WS_G2 + 3 * D_ + d] + bih[3 * D_ + d] + bhh[3 * D_ + d];
    const float si = 1.f / (1.f + expf(-gi));
    const float sf = 1.f / (1.f + expf(-gf));
    const float so = 1.f / (1.f + expf(-go));
    const float cn = sf * c0[d] + si * tanhf(gg);
    const float hn = so * tanhf(cn);
    out[1 + 2 * D_ + d] = hn;
    out[1 + 3 * D_ + d] = cn;
    ws[WS_HN + d] = hn;
  }
}

// ---- kernel 5: fc = lin_w @ h_new + lin_b ----
__global__ __launch_bounds__(256) void k_fc(const float* __restrict__ lw,
    const float* __restrict__ lb, float* __restrict__ ws) {
  const int wid = threadIdx.x >> 6, lane = threadIdx.x & 63;
  const int row = blockIdx.x * 4 + wid;
  float s = wave_dot4(lw + (size_t)row * D_, ws + WS_HN, D_ / 4, lane);
  if (lane == 0) ws[WS_FC + row] = s + lb[row];
}

// ---- kernel 6: l1 = lin1@fc+b, beta = softplus(lin2@fc+b) ----
__global__ __launch_bounds__(256) void k_l1beta(const float* __restrict__ l1w,
    const float* __restrict__ l1b, const float* __restrict__ l2w,
    const float* __restrict__ l2b, float* __restrict__ ws, float* __restrict__ out) {
  const int wid = threadIdx.x >> 6, lane = threadIdx.x & 63;
  const int row = blockIdx.x * 4 + wid;
  float a = wave_dot4(l1w + (size_t)row * D_, ws + WS_FC, D_ / 4, lane);
  float b = wave_dot4(l2w + (size_t)row * D_, ws + WS_FC, D_ / 4, lane);
  if (lane == 0) {
    ws[WS_L1 + row] = a + l1b[row];
    const float x = b + l2b[row];
    out[1 + row] = (x > 20.f) ? x : log1pf(expf(x));
  }
}

// ---- kernel 7: delta = softmax(l1), gamma = dense_w@l1 + dense_b ----
__global__ __launch_bounds__(256) void k_final(const float* __restrict__ dw,
    const float* __restrict__ db, float* __restrict__ ws, float* __restrict__ out) {
  __shared__ float sm[4];
  const int tid = threadIdx.x, lane = tid & 63, wid = tid >> 6;
  float v[8];
  #pragma unroll
  for (int j = 0; j < 8; ++j) v[j] = ws[WS_L1 + tid + j * 256];
  float mx = v[0];
  #pragma unroll
  for (int j = 1; j < 8; ++j) mx = fmaxf(mx, v[j]);
  #pragma unroll
  for (int m = 32; m >= 1; m >>= 1) mx = fmaxf(mx, __shfl_xor(mx, m, 64));
  if (lane == 0) sm[wid] = mx;
  __syncthreads();
  mx = fmaxf(fmaxf(sm[0], sm[1]), fmaxf(sm[2], sm[3]));
  __syncthreads();
  float e[8], ls = 0.f;
  #pragma unroll
  for (int j = 0; j < 8; ++j) { e[j] = expf(v[j] - mx); ls += e[j]; }
  #pragma unroll
  for (int m = 32; m >= 1; m >>= 1) ls += __shfl_xor(ls, m, 64);
  if (lane == 0) sm[wid] = ls;
  __syncthreads();
  ls = sm[0] + sm[1] + sm[2] + sm[3];
  __syncthreads();
  const float inv = 1.f / ls;
  float gp = 0.f;
  #pragma unroll
  for (int j = 0; j < 8; ++j) {
    out[1 + D_ + tid + j * 256] = e[j] * inv;
    gp += v[j] * dw[tid + j * 256];
  }
  #pragma unroll
  for (int m = 32; m >= 1; m >>= 1) gp += __shfl_xor(gp, m, 64);
  if (lane == 0) sm[wid] = gp;
  __syncthreads();
  if (tid == 0) out[0] = sm[0] + sm[1] + sm[2] + sm[3] + db[0];
}

extern "C" void kernel_launch(void* const* d_in, const int* in_sizes, int n_in,
                              void* d_out, int out_size, void* d_ws, size_t ws_size,
                              hipStream_t stream) {
  (void)in_sizes; (void)n_in; (void)out_size;
  const float* data   = (const float*)d_in[0];
  const float* h0     = (const float*)d_in[1];
  const float* c0     = (const float*)d_in[2];
  const float* enc    = (const float*)d_in[3];
  const float* pi     = (const float*)d_in[4];
  const float* Ww     = (const float*)d_in[5];
  const float* Uw     = (const float*)d_in[6];
  const float* Vw     = (const float*)d_in[7];
  const float* lin_w  = (const float*)d_in[8];
  const float* lin_b  = (const float*)d_in[9];
  const float* lin1_w = (const float*)d_in[10];
  const float* lin1_b = (const float*)d_in[11];
  const float* lin2_w = (const float*)d_in[12];
  const float* lin2_b = (const float*)d_in[13];
  const float* dw     = (const float*)d_in[14];
  const float* db     = (const float*)d_in[15];
  const float* Wih    = (const float*)d_in[16];
  const float* Whh    = (const float*)d_in[17];
  const float* bih    = (const float*)d_in[18];
  const float* bhh    = (const float*)d_in[19];
  const int*   ip     = (const int*)d_in[20];
  float* ws  = (float*)d_ws;
  float* out = (float*)d_out;
  const int fast = (ws_size >= WS_FAST_BYTES) ? 1 : 0;

  k_convert<<<1024, 256, 0, stream>>>(Ww, h0, pi, data, ip, enc, Uw, fast, ws);
  if (fast)
    k_gemm_bf16<<<512, 512, 0, stream>>>(Vw, h0, Whh, ws);
  else
    k_gemm_f32<<<dim3(T_ / 128, D_ / 128), 512, 0, stream>>>(enc, Uw, Vw, h0, Whh, ws);
  if (fast)
    k_ctxattn_bf16<<<dim3(D_ / 256, T_ / 256), 256, 0, stream>>>(ip, ws);
  else
    k_ctxattn_f32<<<dim3(D_ / 256, T_ / 256), 256, 0, stream>>>(ip, enc, ws);
  k_gatecell<<<512, 256, 0, stream>>>(Wih, bih, bhh, c0, ws, out);
  k_fc<<<D_ / 4, 256, 0, stream>>>(lin_w, lin_b, ws);
  k_l1beta<<<D_ / 4, 256, 0, stream>>>(lin1_w, lin1_b, lin2_w, lin2_b, ws, out);
  k_final<<<1, 256, 0, stream>>>(dw, db, ws, out);
}

// Round 13
// 128.298 us; speedup vs baseline: 1.0761x; 1.0761x over previous
//
#include <hip/hip_runtime.h>
#include <hip/hip_bf16.h>

#define D_  2048
#define IN_ 512
#define T_  4096
#define G4_ 8192

typedef __attribute__((ext_vector_type(4))) float f32x4;
typedef __attribute__((ext_vector_type(8))) short s16x8;
typedef unsigned short u16;

// ws layout (float offsets)
#define WS_PROD    0                        // T_
#define WS_Q       (T_)                     // D_
#define WS_X       (T_ + D_)                // D_+IN_ : [context | data]
#define WS_PARTIAL (WS_X + D_ + IN_)        // T_*16
#define WS_SCORE   (WS_PARTIAL + T_*16)     // T_ (masked reduced score)
#define WS_GATES   (WS_SCORE + T_)          // G4_ (unused, layout stability)
#define WS_G2      (WS_GATES + G4_)         // G4_  (Whh@h0 partial)
#define WS_FC      (WS_G2 + G4_)            // D_
#define WS_L1      (WS_FC + D_)             // D_
#define WS_HN      (WS_L1 + D_)             // D_
#define WS_BF16    (WS_HN + D_)             // bf16 region (encB, UwB)
#define WS_FAST_BYTES ((size_t)WS_BF16 * 4 + ((size_t)T_ * D_ + (size_t)D_ * D_) * 2)

typedef const __attribute__((address_space(1))) void gas_t;
typedef __attribute__((address_space(3))) void las_t;

__device__ inline u16 bfbits(float f) {
  union { __hip_bfloat16 b; u16 s; } u; u.b = __float2bfloat16(f); return u.s;
}
__device__ inline float bf2f(u16 s) {
  union { unsigned u; float f; } v; v.u = ((unsigned)s) << 16; return v.f;
}

// full-row dot by one wave; returns sum in all lanes
__device__ inline float wave_dot4(const float* __restrict__ w,
                                  const float* __restrict__ x, int n4, int lane) {
  float s = 0.f;
  const f32x4* w4 = (const f32x4*)w;
  const f32x4* x4 = (const f32x4*)x;
  for (int c = lane; c < n4; c += 64) {
    f32x4 a = w4[c], b = x4[c];
    s += a[0]*b[0] + a[1]*b[1] + a[2]*b[2] + a[3]*b[3];
  }
  #pragma unroll
  for (int m = 32; m >= 1; m >>= 1) s += __shfl_xor(s, m, 64);
  return s;
}

// ---- kernel 1: bf16 convert (grid-stride, max BW) + prod + zeroX + data + q ----
__global__ __launch_bounds__(256) void k_convert(const float* __restrict__ Ww,
    const float* __restrict__ h0, const float* __restrict__ pi,
    const float* __restrict__ data, const int* __restrict__ ip,
    const float* __restrict__ enc, const float* __restrict__ Uw,
    int do_convert, float* __restrict__ ws) {
  const int gidx = blockIdx.x * 256 + threadIdx.x;   // 0..262143
  const int nth = 1024 * 256;
  if (do_convert) {
    u16* encB = (u16*)(ws + WS_BF16);
    u16* UwB  = encB + (size_t)T_ * D_;
    for (int c = gidx; c < (T_ * D_) / 8; c += nth) {
      const size_t base = (size_t)c * 8;
      f32x4 v0 = *(const f32x4*)(enc + base);
      f32x4 v1 = *(const f32x4*)(enc + base + 4);
      u16 t[8];
      #pragma unroll
      for (int e = 0; e < 4; ++e) { t[e] = bfbits(v0[e]); t[4 + e] = bfbits(v1[e]); }
      *(s16x8*)&encB[base] = *(s16x8*)&t[0];
    }
    for (int c = gidx; c < (D_ * D_) / 8; c += nth) {
      const size_t base = (size_t)c * 8;
      f32x4 v0 = *(const f32x4*)(Uw + base);
      f32x4 v1 = *(const f32x4*)(Uw + base + 4);
      u16 t[8];
      #pragma unroll
      for (int e = 0; e < 4; ++e) { t[e] = bfbits(v0[e]); t[4 + e] = bfbits(v1[e]); }
      *(s16x8*)&UwB[base] = *(s16x8*)&t[0];
    }
  }
  const int op = ip[0] + 1;
  if (gidx < T_) {
    float p = 0.f;
    if (gidx >= op - 1) {
      int idx = op + T_ - gidx - 2;
      idx = idx < 0 ? 0 : (idx > T_ - 1 ? T_ - 1 : idx);
      p = pi[idx];
    }
    ws[WS_PROD + gidx] = p;
  }
  if (gidx < D_) ws[WS_X + gidx] = 0.f;          // context atomic target
  if (gidx < IN_) ws[WS_X + D_ + gidx] = data[gidx];
  const int gw = gidx >> 6, lane = gidx & 63;
  if (gw < D_) {
    float s = wave_dot4(Ww + (size_t)gw * D_, h0, D_ / 4, lane);
    if (lane == 0) ws[WS_Q + gw] = s;
  }
}

// ---- kernel 2 (fast): bf16 GEMM via global_load_lds, swizzled LDS (r8 exact) ----
__global__ __launch_bounds__(512, 4) void k_gemm_bf16(
    const float* __restrict__ Vw, const float* __restrict__ h0,
    const float* __restrict__ Whh, float* __restrict__ ws) {
  __shared__ __align__(16) u16 Ah[128 * 64];
  __shared__ __align__(16) u16 Bh[128 * 64];
  const u16* encB = (const u16*)(ws + WS_BF16);
  const u16* UwB  = encB + (size_t)T_ * D_;
  const int tid = threadIdx.x, lane = tid & 63, wid = tid >> 6;
  const int wr = wid >> 2, wc = wid & 3;         // 2 x 4 wave grid
  const int g = lane >> 4, lr = lane & 15;
  const int bid = blockIdx.x;
  // XCD-chunked swizzle: XCD k owns mb in {4k..4k+3} for all nb
  const int wgid = (bid & 7) * 64 + (bid >> 3);
  const int mb = wgid >> 4, nb = wgid & 15;

  f32x4 acc[4][2];
  #pragma unroll
  for (int m = 0; m < 4; ++m)
    #pragma unroll
    for (int n = 0; n < 2; ++n) acc[m][n] = (f32x4){0.f, 0.f, 0.f, 0.f};

  // staging: 1024 16B-chunks per 128x64 tile; thread covers c = tid, tid+512.
  // rule #21: linear LDS dest + inverse-swizzled global source + swizzled read.
  const int c0 = tid,        r0 = c0 >> 3, s0 = (c0 & 7) ^ (r0 & 7);
  const int c1 = tid + 512,  r1 = c1 >> 3, s1 = (c1 & 7) ^ (r1 & 7);
  const u16* ga0 = encB + (size_t)(mb * 128 + r0) * D_ + s0 * 8;
  const u16* ga1 = encB + (size_t)(mb * 128 + r1) * D_ + s1 * 8;
  const u16* gb0 = UwB  + (size_t)(nb * 128 + r0) * D_ + s0 * 8;
  const u16* gb1 = UwB  + (size_t)(nb * 128 + r1) * D_ + s1 * 8;
  u16* la0 = &Ah[c0 * 8]; u16* la1 = &Ah[c1 * 8];
  u16* lb0 = &Bh[c0 * 8]; u16* lb1 = &Bh[c1 * 8];

  for (int ks = 0; ks < D_ / 64; ++ks) {
    __syncthreads();   // previous iteration's LDS reads complete
    __builtin_amdgcn_global_load_lds((gas_t*)(ga0 + ks * 64), (las_t*)la0, 16, 0, 0);
    __builtin_amdgcn_global_load_lds((gas_t*)(ga1 + ks * 64), (las_t*)la1, 16, 0, 0);
    __builtin_amdgcn_global_load_lds((gas_t*)(gb0 + ks * 64), (las_t*)lb0, 16, 0, 0);
    __builtin_amdgcn_global_load_lds((gas_t*)(gb1 + ks * 64), (las_t*)lb1, 16, 0, 0);
    __syncthreads();   // compiler drains vmcnt before barrier
    #pragma unroll
    for (int kk = 0; kk < 2; ++kk) {
      const int koff = kk * 64 + g * 16;   // byte offset within 128B row
      s16x8 af[4], bf[2];
      #pragma unroll
      for (int m = 0; m < 4; ++m) {
        const int r = wr * 64 + m * 16 + lr;
        af[m] = *(const s16x8*)((const char*)Ah + r * 128 + (koff ^ ((r & 7) << 4)));
      }
      #pragma unroll
      for (int n = 0; n < 2; ++n) {
        const int r = wc * 32 + n * 16 + lr;
        bf[n] = *(const s16x8*)((const char*)Bh + r * 128 + (koff ^ ((r & 7) << 4)));
      }
      #pragma unroll
      for (int m = 0; m < 4; ++m)
        #pragma unroll
        for (int n = 0; n < 2; ++n)
          acc[m][n] = __builtin_amdgcn_mfma_f32_16x16x32_bf16(af[m], bf[n], acc[m][n], 0, 0, 0);
    }
  }

  // epilogue: per-row partial of score = sum_d V[d]*tanh(q[d] + prod[t]*C[t][d])
  const float* q    = ws + WS_Q;
  const float* prod = ws + WS_PROD;
  float Vv[2], qv[2];
  #pragma unroll
  for (int n = 0; n < 2; ++n) {
    const int d = nb * 128 + wc * 32 + n * 16 + lr;
    Vv[n] = Vw[d]; qv[n] = q[d];
  }
  __syncthreads();
  float* red = (float*)Ah;   // 128 x 4 floats
  #pragma unroll
  for (int m = 0; m < 4; ++m) {
    #pragma unroll
    for (int r = 0; r < 4; ++r) {
      const int t_loc = wr * 64 + m * 16 + g * 4 + r;
      const float p = prod[mb * 128 + t_loc];
      float s = Vv[0] * tanhf(qv[0] + p * acc[m][0][r])
              + Vv[1] * tanhf(qv[1] + p * acc[m][1][r]);
      s += __shfl_xor(s, 1, 64);
      s += __shfl_xor(s, 2, 64);
      s += __shfl_xor(s, 4, 64);
      s += __shfl_xor(s, 8, 64);
      if (lr == 0) red[t_loc * 4 + wc] = s;
    }
  }
  __syncthreads();
  if (tid < 128) {
    const float s = red[tid * 4] + red[tid * 4 + 1] + red[tid * 4 + 2] + red[tid * 4 + 3];
    ws[WS_PARTIAL + (size_t)(mb * 128 + tid) * 16 + nb] = s;
  }

  // Whh @ h0 tail: 16 rows per block (overlaps other blocks' GEMM)
  const int rbase = bid * 16 + wid * 2;
  #pragma unroll
  for (int rr = 0; rr < 2; ++rr) {
    const int row = rbase + rr;
    float s = wave_dot4(Whh + (size_t)row * D_, h0, D_ / 4, lane);
    if (lane == 0) ws[WS_G2 + row] = s;
  }
}

// ---- kernel 2 (fallback): fp32-load in-kernel-convert GEMM ----
__global__ __launch_bounds__(512, 4) void k_gemm_f32(
    const float* __restrict__ enc, const float* __restrict__ Uw,
    const float* __restrict__ Vw, const float* __restrict__ h0,
    const float* __restrict__ Whh, float* __restrict__ ws) {
  __shared__ __align__(16) u16 sbuf[2 * 128 * 40];
  u16* Ah = sbuf;
  u16* Bh = sbuf + 128 * 40;
  const int tid = threadIdx.x;
  const int lane = tid & 63, wid = tid >> 6;
  const int wr = wid >> 2, wc = wid & 3;
  const int g = lane >> 4, lr = lane & 15;
  const int mb = blockIdx.x, nb = blockIdx.y;

  f32x4 acc[4][2];
  #pragma unroll
  for (int m = 0; m < 4; ++m)
    #pragma unroll
    for (int n = 0; n < 2; ++n) acc[m][n] = (f32x4){0.f, 0.f, 0.f, 0.f};

  const int srow = tid >> 2;
  const int scol = (tid & 3) * 8;
  const float* pa0 = enc + (size_t)(mb * 128 + srow) * D_ + scol;
  const float* pb0 = Uw  + (size_t)(nb * 128 + srow) * D_ + scol;
  const int sidx = srow * 40 + scol;

  f32x4 an0 = *(const f32x4*)(pa0);
  f32x4 an1 = *(const f32x4*)(pa0 + 4);
  f32x4 bn0 = *(const f32x4*)(pb0);
  f32x4 bn1 = *(const f32x4*)(pb0 + 4);

  for (int ks = 0; ks < 64; ++ks) {
    f32x4 a0 = an0, a1 = an1, b0 = bn0, b1 = bn1;
    if (ks < 63) {
      an0 = *(const f32x4*)(pa0 + (ks + 1) * 32);
      an1 = *(const f32x4*)(pa0 + (ks + 1) * 32 + 4);
      bn0 = *(const f32x4*)(pb0 + (ks + 1) * 32);
      bn1 = *(const f32x4*)(pb0 + (ks + 1) * 32 + 4);
    }
    __syncthreads();
    __align__(16) u16 ah[8], bh[8];
    #pragma unroll
    for (int e = 0; e < 4; ++e) {
      ah[e] = bfbits(a0[e]); ah[4 + e] = bfbits(a1[e]);
      bh[e] = bfbits(b0[e]); bh[4 + e] = bfbits(b1[e]);
    }
    *(s16x8*)&Ah[sidx] = *(s16x8*)&ah[0];
    *(s16x8*)&Bh[sidx] = *(s16x8*)&bh[0];
    __syncthreads();

    s16x8 af[4], bf[2];
    #pragma unroll
    for (int m = 0; m < 4; ++m)
      af[m] = *(const s16x8*)&Ah[(wr * 64 + m * 16 + lr) * 40 + g * 8];
    #pragma unroll
    for (int n = 0; n < 2; ++n)
      bf[n] = *(const s16x8*)&Bh[(wc * 32 + n * 16 + lr) * 40 + g * 8];
    #pragma unroll
    for (int m = 0; m < 4; ++m)
      #pragma unroll
      for (int n = 0; n < 2; ++n)
        acc[m][n] = __builtin_amdgcn_mfma_f32_16x16x32_bf16(af[m], bf[n], acc[m][n], 0, 0, 0);
  }

  const float* q    = ws + WS_Q;
  const float* prod = ws + WS_PROD;
  float Vv[2], qv[2];
  #pragma unroll
  for (int n = 0; n < 2; ++n) {
    const int d = nb * 128 + wc * 32 + n * 16 + lr;
    Vv[n] = Vw[d]; qv[n] = q[d];
  }
  __syncthreads();
  float* red = (float*)sbuf;
  #pragma unroll
  for (int m = 0; m < 4; ++m) {
    #pragma unroll
    for (int r = 0; r < 4; ++r) {
      const int t_loc = wr * 64 + m * 16 + g * 4 + r;
      const float p = prod[mb * 128 + t_loc];
      float s = Vv[0] * tanhf(qv[0] + p * acc[m][0][r])
              + Vv[1] * tanhf(qv[1] + p * acc[m][1][r]);
      s += __shfl_xor(s, 1, 64);
      s += __shfl_xor(s, 2, 64);
      s += __shfl_xor(s, 4, 64);
      s += __shfl_xor(s, 8, 64);
      if (lr == 0) red[t_loc * 4 + wc] = s;
    }
  }
  __syncthreads();
  if (tid < 128) {
    const float s = red[tid * 4] + red[tid * 4 + 1] + red[tid * 4 + 2] + red[tid * 4 + 3];
    ws[WS_PARTIAL + (size_t)(mb * 128 + tid) * 16 + nb] = s;
  }
  const int flat = blockIdx.y * gridDim.x + blockIdx.x;
  const int rbase = flat * 16 + wid * 2;
  #pragma unroll
  for (int rr = 0; rr < 2; ++rr) {
    const int row = rbase + rr;
    float s = wave_dot4(Whh + (size_t)row * D_, h0, D_ / 4, lane);
    if (lane == 0) ws[WS_G2 + row] = s;
  }
}

// ---- kernel 3: reduce partials -> masked score ----
__global__ __launch_bounds__(256) void k_score(const int* __restrict__ ip,
                                               float* __restrict__ ws) {
  const int t = blockIdx.x * 256 + threadIdx.x;
  const int op = ip[0] + 1;
  const f32x4* p = (const f32x4*)(ws + WS_PARTIAL + (size_t)t * 16);
  f32x4 p0 = p[0], p1 = p[1], p2 = p[2], p3 = p[3];
  float s = (p0[0]+p0[1]+p0[2]+p0[3]) + (p1[0]+p1[1]+p1[2]+p1[3])
          + (p2[0]+p2[1]+p2[2]+p2[3]) + (p3[0]+p3[1]+p3[2]+p3[3]);
  ws[WS_SCORE + t] = (t < op) ? 0.f : s;
}

// ---- kernel 4: per-block local softmax + context chunk ----
__global__ __launch_bounds__(256) void k_ctxattn_bf16(float* __restrict__ ws) {
  __shared__ float sred[4];
  __shared__ float satt[256];
  const u16* encB = (const u16*)(ws + WS_BF16);
  const int tid = threadIdx.x, lane = tid & 63, wid = tid >> 6;
  const float* score = ws + WS_SCORE;
  float lv[16];
  #pragma unroll
  for (int j = 0; j < 16; ++j) lv[j] = score[tid + j * 256];
  float mx = lv[0];
  #pragma unroll
  for (int j = 1; j < 16; ++j) mx = fmaxf(mx, lv[j]);
  #pragma unroll
  for (int m = 32; m >= 1; m >>= 1) mx = fmaxf(mx, __shfl_xor(mx, m, 64));
  if (lane == 0) sred[wid] = mx;
  __syncthreads();
  mx = fmaxf(fmaxf(sred[0], sred[1]), fmaxf(sred[2], sred[3]));
  __syncthreads();
  float ls = 0.f;
  #pragma unroll
  for (int j = 0; j < 16; ++j) ls += expf(lv[j] - mx);
  #pragma unroll
  for (int m = 32; m >= 1; m >>= 1) ls += __shfl_xor(ls, m, 64);
  if (lane == 0) sred[wid] = ls;
  __syncthreads();
  const float inv = 1.f / (sred[0] + sred[1] + sred[2] + sred[3]);
  const int t0 = blockIdx.y * 256;
  satt[tid] = expf(score[t0 + tid] - mx) * inv;
  __syncthreads();
  const int d = blockIdx.x * 256 + threadIdx.x;
  float s = 0.f;
  for (int t = 0; t < 256; ++t) s += satt[t] * bf2f(encB[(size_t)(t0 + t) * D_ + d]);
  atomicAdd(&ws[WS_X + d], s);
}
__global__ __launch_bounds__(256) void k_ctxattn_f32(const float* __restrict__ enc,
                                                     float* __restrict__ ws) {
  __shared__ float sred[4];
  __shared__ float satt[256];
  const int tid = threadIdx.x, lane = tid & 63, wid = tid >> 6;
  const float* score = ws + WS_SCORE;
  float lv[16];
  #pragma unroll
  for (int j = 0; j < 16; ++j) lv[j] = score[tid + j * 256];
  float mx = lv[0];
  #pragma unroll
  for (int j = 1; j < 16; ++j) mx = fmaxf(mx, lv[j]);
  #pragma unroll
  for (int m = 32; m >= 1; m >>= 1) mx = fmaxf(mx, __shfl_xor(mx, m, 64));
  if (lane == 0) sred[wid] = mx;
  __syncthreads();
  mx = fmaxf(fmaxf(sred[0], sred[1]), fmaxf(sred[2], sred[3]));
  __syncthreads();
  float ls = 0.f;
  #pragma unroll
  for (int j = 0; j < 16; ++j) ls += expf(lv[j] - mx);
  #pragma unroll
  for (int m = 32; m >= 1; m >>= 1) ls += __shfl_xor(ls, m, 64);
  if (lane == 0) sred[wid] = ls;
  __syncthreads();
  const float inv = 1.f / (sred[0] + sred[1] + sred[2] + sred[3]);
  const int t0 = blockIdx.y * 256;
  satt[tid] = expf(score[t0 + tid] - mx) * inv;
  __syncthreads();
  const int d = blockIdx.x * 256 + threadIdx.x;
  float s = 0.f;
  for (int t = 0; t < 256; ++t) s += satt[t] * enc[(size_t)(t0 + t) * D_ + d];
  atomicAdd(&ws[WS_X + d], s);
}

// ---- kernel 5: fused LSTM gates + cell (full-row dot vs [ctx|data]) ----
__global__ __launch_bounds__(256) void k_gatecell(const float* __restrict__ Wih,
    const float* __restrict__ bih, const float* __restrict__ bhh,
    const float* __restrict__ c0, float* __restrict__ ws, float* __restrict__ out) {
  const int wid = threadIdx.x >> 6, lane = threadIdx.x & 63;
  const int d = blockIdx.x * 4 + wid;            // 0..2047
  const f32x4* x4 = (const f32x4*)(ws + WS_X);
  const f32x4* r0 = (const f32x4*)(Wih + (size_t)(0 * D_ + d) * (D_ + IN_));
  const f32x4* r1 = (const f32x4*)(Wih + (size_t)(1 * D_ + d) * (D_ + IN_));
  const f32x4* r2 = (const f32x4*)(Wih + (size_t)(2 * D_ + d) * (D_ + IN_));
  const f32x4* r3 = (const f32x4*)(Wih + (size_t)(3 * D_ + d) * (D_ + IN_));
  float s0 = 0.f, s1 = 0.f, s2 = 0.f, s3 = 0.f;
  for (int c = lane; c < (D_ + IN_) / 4; c += 64) {
    f32x4 x = x4[c];
    f32x4 a0 = r0[c], a1 = r1[c], a2 = r2[c], a3 = r3[c];
    s0 += a0[0]*x[0] + a0[1]*x[1] + a0[2]*x[2] + a0[3]*x[3];
    s1 += a1[0]*x[0] + a1[1]*x[1] + a1[2]*x[2] + a1[3]*x[3];
    s2 += a2[0]*x[0] + a2[1]*x[1] + a2[2]*x[2] + a2[3]*x[3];
    s3 += a3[0]*x[0] + a3[1]*x[1] + a3[2]*x[2] + a3[3]*x[3];
  }
  #pragma unroll
  for (int m = 32; m >= 1; m >>= 1) {
    s0 += __shfl_xor(s0, m, 64);
    s1 += __shfl_xor(s1, m, 64);
    s2 += __shfl_xor(s2, m, 64);
    s3 += __shfl_xor(s3, m, 64);
  }
  if (lane == 0) {
    const float gi = s0 + ws[WS_G2 + 0 * D_ + d] + bih[0 * D_ + d] + bhh[0 * D_ + d];
    const float gf = s1 + ws[WS_G2 + 1 * D_ + d] + bih[1 * D_ + d] + bhh[1 * D_ + d];
    const float gg = s2 + ws[WS_G2 + 2 * D_ + d] + bih[2 * D_ + d] + bhh[2 * D_ + d];
    const float go = s3 + ws[WS_G2 + 3 * D_ + d] + bih[3 * D_ + d] + bhh[3 * D_ + d];
    const float si = 1.f / (1.f + expf(-gi));
    const float sf = 1.f / (1.f + expf(-gf));
    const float so = 1.f / (1.f + expf(-go));
    const float cn = sf * c0[d] + si * tanhf(gg);
    const float hn = so * tanhf(cn);
    out[1 + 2 * D_ + d] = hn;
    out[1 + 3 * D_ + d] = cn;
    ws[WS_HN + d] = hn;
  }
}

// ---- kernel 6: fc = lin_w @ h_new + lin_b ----
__global__ __launch_bounds__(256) void k_fc(const float* __restrict__ lw,
    const float* __restrict__ lb, float* __restrict__ ws) {
  const int wid = threadIdx.x >> 6, lane = threadIdx.x & 63;
  const int row = blockIdx.x * 4 + wid;
  float s = wave_dot4(lw + (size_t)row * D_, ws + WS_HN, D_ / 4, lane);
  if (lane == 0) ws[WS_FC + row] = s + lb[row];
}

// ---- kernel 7: l1 = lin1@fc+b, beta = softplus(lin2@fc+b) ----
__global__ __launch_bounds__(256) void k_l1beta(const float* __restrict__ l1w,
    const float* __restrict__ l1b, const float* __restrict__ l2w,
    const float* __restrict__ l2b, float* __restrict__ ws, float* __restrict__ out) {
  const int wid = threadIdx.x >> 6, lane = threadIdx.x & 63;
  const int row = blockIdx.x * 4 + wid;
  float a = wave_dot4(l1w + (size_t)row * D_, ws + WS_FC, D_ / 4, lane);
  float b = wave_dot4(l2w + (size_t)row * D_, ws + WS_FC, D_ / 4, lane);
  if (lane == 0) {
    ws[WS_L1 + row] = a + l1b[row];
    const float x = b + l2b[row];
    out[1 + row] = (x > 20.f) ? x : log1pf(expf(x));
  }
}

// ---- kernel 8: delta = softmax(l1), gamma = dense_w@l1 + dense_b ----
__global__ __launch_bounds__(256) void k_final(const float* __restrict__ dw,
    const float* __restrict__ db, float* __restrict__ ws, float* __restrict__ out) {
  __shared__ float sm[4];
  const int tid = threadIdx.x, lane = tid & 63, wid = tid >> 6;
  float v[8];
  #pragma unroll
  for (int j = 0; j < 8; ++j) v[j] = ws[WS_L1 + tid + j * 256];
  float mx = v[0];
  #pragma unroll
  for (int j = 1; j < 8; ++j) mx = fmaxf(mx, v[j]);
  #pragma unroll
  for (int m = 32; m >= 1; m >>= 1) mx = fmaxf(mx, __shfl_xor(mx, m, 64));
  if (lane == 0) sm[wid] = mx;
  __syncthreads();
  mx = fmaxf(fmaxf(sm[0], sm[1]), fmaxf(sm[2], sm[3]));
  __syncthreads();
  float e[8], ls = 0.f;
  #pragma unroll
  for (int j = 0; j < 8; ++j) { e[j] = expf(v[j] - mx); ls += e[j]; }
  #pragma unroll
  for (int m = 32; m >= 1; m >>= 1) ls += __shfl_xor(ls, m, 64);
  if (lane == 0) sm[wid] = ls;
  __syncthreads();
  ls = sm[0] + sm[1] + sm[2] + sm[3];
  __syncthreads();
  const float inv = 1.f / ls;
  float gp = 0.f;
  #pragma unroll
  for (int j = 0; j < 8; ++j) {
    out[1 + D_ + tid + j * 256] = e[j] * inv;
    gp += v[j] * dw[tid + j * 256];
  }
  #pragma unroll
  for (int m = 32; m >= 1; m >>= 1) gp += __shfl_xor(gp, m, 64);
  if (lane == 0) sm[wid] = gp;
  __syncthreads();
  if (tid == 0) out[0] = sm[0] + sm[1] + sm[2] + sm[3] + db[0];
}

extern "C" void kernel_launch(void* const* d_in, const int* in_sizes, int n_in,
                              void* d_out, int out_size, void* d_ws, size_t ws_size,
                              hipStream_t stream) {
  (void)in_sizes; (void)n_in; (void)out_size;
  const float* data   = (const float*)d_in[0];
  const float* h0     = (const float*)d_in[1];
  const float* c0     = (const float*)d_in[2];
  const float* enc    = (const float*)d_in[3];
  const float* pi     = (const float*)d_in[4];
  const float* Ww     = (const float*)d_in[5];
  const float* Uw     = (const float*)d_in[6];
  const float* Vw     = (const float*)d_in[7];
  const float* lin_w  = (const float*)d_in[8];
  const float* lin_b  = (const float*)d_in[9];
  const float* lin1_w = (const float*)d_in[10];
  const float* lin1_b = (const float*)d_in[11];
  const float* lin2_w = (const float*)d_in[12];
  const float* lin2_b = (const float*)d_in[13];
  const float* dw     = (const float*)d_in[14];
  const float* db     = (const float*)d_in[15];
  const float* Wih    = (const float*)d_in[16];
  const float* Whh    = (const float*)d_in[17];
  const float* bih    = (const float*)d_in[18];
  const float* bhh    = (const float*)d_in[19];
  const int*   ip     = (const int*)d_in[20];
  float* ws  = (float*)d_ws;
  float* out = (float*)d_out;
  const int fast = (ws_size >= WS_FAST_BYTES) ? 1 : 0;

  k_convert<<<1024, 256, 0, stream>>>(Ww, h0, pi, data, ip, enc, Uw, fast, ws);
  if (fast)
    k_gemm_bf16<<<512, 512, 0, stream>>>(Vw, h0, Whh, ws);
  else
    k_gemm_f32<<<dim3(T_ / 128, D_ / 128), 512, 0, stream>>>(enc, Uw, Vw, h0, Whh, ws);
  k_score<<<T_ / 256, 256, 0, stream>>>(ip, ws);
  if (fast)
    k_ctxattn_bf16<<<dim3(D_ / 256, T_ / 256), 256, 0, stream>>>(ws);
  else
    k_ctxattn_f32<<<dim3(D_ / 256, T_ / 256), 256, 0, stream>>>(enc, ws);
  k_gatecell<<<512, 256, 0, stream>>>(Wih, bih, bhh, c0, ws, out);
  k_fc<<<D_ / 4, 256, 0, stream>>>(lin_w, lin_b, ws);
  k_l1beta<<<D_ / 4, 256, 0, stream>>>(lin1_w, lin1_b, lin2_w, lin2_b, ws, out);
  k_final<<<1, 256, 0, stream>>>(dw, db, ws, out);
}